// Round 4
// baseline (8283.379 us; speedup 1.0000x reference)
//
#include <hip/hip_runtime.h>
#include <math.h>

#define D_IN   512
#define HID    1024
#define SEQ    512
#define NBATCH 64
#define K3     3072
#define KTOT   1536
#define WB_ELEMS (K3 * KTOT)
#define NBLK   256

typedef __attribute__((ext_vector_type(8))) short short8;
typedef __attribute__((ext_vector_type(4))) float f32x4;

#define MFMA(a, b, c) __builtin_amdgcn_mfma_f32_16x16x32_bf16((a), (b), (c), 0, 0, 0)

// ---------------- build fused transposed weight planes (hi/lo bf16) ----------------
__global__ __launch_bounds__(256) void build_wt(const float* __restrict__ Win,
                                                const float* __restrict__ Wh,
                                                __bf16* __restrict__ WBh,
                                                __bf16* __restrict__ WBl) {
    int idx = blockIdx.x * 256 + threadIdx.x;
    if (idx >= WB_ELEMS) return;
    int k   = idx % KTOT;
    int col = idx / KTOT;
    float v = (k < D_IN) ? Win[(size_t)k * K3 + col]
                         : Wh[(size_t)(k - D_IN) * K3 + col];
    __bf16 hi = (__bf16)v;
    WBh[idx] = hi;
    WBl[idx] = (__bf16)(v - (float)hi);
}

__device__ __forceinline__ void cvt8(const f32x4& v0, const f32x4& v1,
                                     short8& ahi, short8& alo) {
    float af[8] = {v0[0], v0[1], v0[2], v0[3], v1[0], v1[1], v1[2], v1[3]};
    #pragma unroll
    for (int j = 0; j < 8; ++j) {
        __bf16 hb = (__bf16)af[j];
        __bf16 lb = (__bf16)(af[j] - (float)hb);
        ahi[j] = __builtin_bit_cast(short, hb);
        alo[j] = __builtin_bit_cast(short, lb);
    }
}

// ---------------- persistent GRU: all 512 steps in one kernel ----------------
// Grid: 256 blocks x 1024 threads (16 waves). Co-residency: 16 waves/block,
// <=128 VGPR (launch_bounds 1024,4) -> 1 block/CU fits; grid == 256 == #CUs.
// Block (mq = j&3, nb = xcd + 8*(j>>2)), xcd = bid&7  [XCD-sharer swizzle].
//   batches [16mq,16mq+16), column-triples {cb+i, 1024+cb+i, 2048+cb+i}.
// Waves 0-7: x-part, K-slice 64 (2 iters, normal loads).
// Waves 8-15: h-part, K-slice 128 (4 iters, sc0sc1 L2-bypass loads).
// Inter-step sync: tree barrier (8 group counters + root), monotonic counts.
__global__ __launch_bounds__(1024, 4) void gru_persist(
        const float* __restrict__ x, const float* __restrict__ bin,
        const __bf16* __restrict__ WBh, const __bf16* __restrict__ WBl,
        float* __restrict__ out, unsigned* __restrict__ bar) {
    __shared__ float red[16][3][4][64];   // [wave][z,r,n][reg][lane] = 48KB
    float* hall = out + NBATCH * HID;

    const int tid = threadIdx.x;
    const int l   = tid & 63;
    const int w   = tid >> 6;              // 0..15
    const int xcd = blockIdx.x & 7;
    const int j   = blockIdx.x >> 3;
    const int nb  = xcd + 8 * (j >> 2);
    const int mq  = j & 3;
    const int cb  = nb * 16;

    const int m    = mq * 16 + (l & 15);
    const int koff = (l >> 4) * 8;
    const int colz = cb + (l & 15);
    const bool isx = (w < 8);
    const int kw0  = isx ? (w * 64) : (D_IN + (w - 8) * 128);

    // epilogue-thread constants (tid < 256)
    const int r2 = tid >> 6;
    const int l2 = tid & 63;
    const int be = mq * 16 + (l2 >> 4) * 4 + r2;   // batch  (C layout, m89)
    const int ce = cb + (l2 & 15);                 // column
    float bz = 0.f, br = 0.f, bnb = 0.f, hreg = 0.f;
    if (tid < 256) {
        bz  = bin[ce];
        br  = bin[HID + ce];
        bnb = bin[2 * HID + ce];
    }

    for (int t = 0; t < SEQ; ++t) {
        f32x4 accZ = {0.f, 0.f, 0.f, 0.f};
        f32x4 accR = {0.f, 0.f, 0.f, 0.f};
        f32x4 accN = {0.f, 0.f, 0.f, 0.f};   // nx for x-waves, nh for h-waves

        if (isx) {
            #pragma unroll
            for (int s = 0; s < 2; ++s) {
                const int ks = kw0 + s * 32;
                const float* ap = x + ((size_t)m * SEQ + t) * D_IN + ks + koff;
                f32x4 v0 = *(const f32x4*)ap;
                f32x4 v1 = *(const f32x4*)(ap + 4);
                short8 ahi, alo;
                cvt8(v0, v1, ahi, alo);
                const size_t o0 = (size_t)colz * KTOT + ks + koff;
                const size_t o1 = o0 + (size_t)HID * KTOT;
                const size_t o2 = o1 + (size_t)HID * KTOT;
                short8 bzh = *(const short8*)(WBh + o0);
                short8 bzl = *(const short8*)(WBl + o0);
                short8 brh = *(const short8*)(WBh + o1);
                short8 brl = *(const short8*)(WBl + o1);
                short8 bnh = *(const short8*)(WBh + o2);
                short8 bnl = *(const short8*)(WBl + o2);
                accZ = MFMA(ahi, bzh, accZ); accZ = MFMA(ahi, bzl, accZ); accZ = MFMA(alo, bzh, accZ);
                accR = MFMA(ahi, brh, accR); accR = MFMA(ahi, brl, accR); accR = MFMA(alo, brh, accR);
                accN = MFMA(ahi, bnh, accN); accN = MFMA(ahi, bnl, accN); accN = MFMA(alo, bnh, accN);
            }
        } else if (t > 0) {
            #pragma unroll
            for (int s = 0; s < 4; ++s) {
                const int ks = kw0 + s * 32;
                const float* ap = hall + ((size_t)m * SEQ + (t - 1)) * HID + (ks - D_IN) + koff;
                f32x4 v0, v1;
                // L2-bypass coherent read of h written by other XCDs last step
                asm volatile("global_load_dwordx4 %0, %2, off sc0 sc1\n\t"
                             "global_load_dwordx4 %1, %2, off offset:16 sc0 sc1\n\t"
                             "s_waitcnt vmcnt(0)"
                             : "=&v"(v0), "=&v"(v1)
                             : "v"(ap));
                short8 ahi, alo;
                cvt8(v0, v1, ahi, alo);
                const size_t o0 = (size_t)colz * KTOT + ks + koff;
                const size_t o1 = o0 + (size_t)HID * KTOT;
                const size_t o2 = o1 + (size_t)HID * KTOT;
                short8 bzh = *(const short8*)(WBh + o0);
                short8 bzl = *(const short8*)(WBl + o0);
                short8 brh = *(const short8*)(WBh + o1);
                short8 brl = *(const short8*)(WBl + o1);
                short8 bnh = *(const short8*)(WBh + o2);
                short8 bnl = *(const short8*)(WBl + o2);
                accZ = MFMA(ahi, bzh, accZ); accZ = MFMA(ahi, bzl, accZ); accZ = MFMA(alo, bzh, accZ);
                accR = MFMA(ahi, brh, accR); accR = MFMA(ahi, brl, accR); accR = MFMA(alo, brh, accR);
                accN = MFMA(ahi, bnh, accN); accN = MFMA(ahi, bnl, accN); accN = MFMA(alo, bnh, accN);
            }
        }

        #pragma unroll
        for (int r = 0; r < 4; ++r) {
            red[w][0][r][l] = accZ[r];
            red[w][1][r][l] = accR[r];
            red[w][2][r][l] = accN[r];
        }
        __syncthreads();

        if (tid < 256) {
            float sz = 0.f, sr = 0.f, snx = 0.f, snh = 0.f;
            #pragma unroll
            for (int wv = 0; wv < 8; ++wv) {
                sz  += red[wv][0][r2][l2];
                sr  += red[wv][1][r2][l2];
                snx += red[wv][2][r2][l2];
            }
            #pragma unroll
            for (int wv = 8; wv < 16; ++wv) {
                sz  += red[wv][0][r2][l2];
                sr  += red[wv][1][r2][l2];
                snh += red[wv][2][r2][l2];
            }
            float z   = 1.f / (1.f + __expf(-(sz + bz)));
            float rr  = 1.f / (1.f + __expf(-(sr + br)));
            float pre = snx + bnb + rr * snh;
            float e2  = __expf(2.f * pre);
            float n   = 1.f - 2.f / (e2 + 1.f);
            float h   = (1.f - z) * n + z * hreg;
            hreg = h;   // carry own h: epilogue thread <-> (be,ce) is fixed
            float* hw = hall + ((size_t)be * SEQ + t) * HID + ce;
            // write-through to L3 so other XCDs' sc1 reads see it next step
            asm volatile("global_store_dword %0, %1, off sc0 sc1"
                         :: "v"(hw), "v"(h) : "memory");
            if (t == SEQ - 1) out[(size_t)be * HID + ce] = h;
        }
        asm volatile("s_waitcnt vmcnt(0)" ::: "memory");
        __syncthreads();

        // ---- tree grid-barrier, monotonic generation counts ----
        if (tid == 0) {
            const int g = blockIdx.x >> 5;   // 8 groups of 32 blocks
            unsigned old = __hip_atomic_fetch_add(&bar[g * 16], 1u,
                                __ATOMIC_RELEASE, __HIP_MEMORY_SCOPE_AGENT);
            if (old == (unsigned)(t + 1) * 32u - 1u) {
                __hip_atomic_fetch_add(&bar[128], 1u,
                                __ATOMIC_RELEASE, __HIP_MEMORY_SCOPE_AGENT);
            }
            const unsigned target = (unsigned)(t + 1) * 8u;
            while (__hip_atomic_load(&bar[128], __ATOMIC_RELAXED,
                                     __HIP_MEMORY_SCOPE_AGENT) < target)
                __builtin_amdgcn_s_sleep(1);
        }
        __syncthreads();
    }
}

extern "C" void kernel_launch(void* const* d_in, const int* in_sizes, int n_in,
                              void* d_out, int out_size, void* d_ws, size_t ws_size,
                              hipStream_t stream) {
    const float* x   = (const float*)d_in[0];
    const float* Win = (const float*)d_in[1];
    const float* bin = (const float*)d_in[2];
    const float* Wh  = (const float*)d_in[3];
    float* out = (float*)d_out;

    __bf16* WBh = (__bf16*)d_ws;                       // 9.44 MB
    __bf16* WBl = (__bf16*)d_ws + (size_t)WB_ELEMS;    // 9.44 MB
    unsigned* bar = (unsigned*)((char*)d_ws + (size_t)2 * WB_ELEMS * sizeof(__bf16));

    hipMemsetAsync(bar, 0, 1024, stream);   // deterministic: reset every call
    hipLaunchKernelGGL(build_wt, dim3((WB_ELEMS + 255) / 256), dim3(256), 0, stream,
                       Win, Wh, WBh, WBl);
    hipLaunchKernelGGL(gru_persist, dim3(NBLK), dim3(1024), 0, stream,
                       x, bin, WBh, WBl, out, bar);
}